// Round 15
// baseline (625.856 us; speedup 1.0000x reference)
//
#include <hip/hip_runtime.h>
#include <cfloat>

#define NEG_SLOPE 0.2f

// ---------------- CSR build ----------------
__global__ __launch_bounds__(256) void zero_kernel(int* __restrict__ counts,
                                                   int* __restrict__ cursor, int n) {
    int gid = blockIdx.x * 256 + threadIdx.x;
    if (gid < n) { counts[gid] = 0; cursor[gid] = 0; }
}

__global__ __launch_bounds__(256) void count_kernel(const int* __restrict__ dst,
                                                    int* __restrict__ counts, int E) {
    int e = blockIdx.x * 256 + threadIdx.x;
    if (e < E) atomicAdd(&counts[dst[e]], 1);
}

// ---- hierarchical scan: 1024 elements per block ----
__global__ __launch_bounds__(256) void scan_bsums_kernel(const int* __restrict__ counts,
                                                         int* __restrict__ bsums, int N) {
    int t = threadIdx.x;
    int base = blockIdx.x * 1024 + t * 4;
    int s = 0;
    #pragma unroll
    for (int i = 0; i < 4; ++i) { int idx = base + i; if (idx < N) s += counts[idx]; }
    #pragma unroll
    for (int d = 1; d < 64; d <<= 1) s += __shfl_xor(s, d);
    __shared__ int ws[4];
    if ((t & 63) == 0) ws[t >> 6] = s;
    __syncthreads();
    if (t == 0) bsums[blockIdx.x] = ws[0] + ws[1] + ws[2] + ws[3];
}

__global__ __launch_bounds__(64) void scan_bscan_kernel(int* __restrict__ bsums, int NB) {
    int t = threadIdx.x;
    int v = (t < NB) ? bsums[t] : 0;
    int x = v;
    #pragma unroll
    for (int d = 1; d < 64; d <<= 1) {
        int y = __shfl_up(x, d);
        if (t >= d) x += y;
    }
    if (t < NB) bsums[t] = x - v;   // exclusive
}

__global__ __launch_bounds__(256) void scan_final_kernel(const int* __restrict__ counts,
                                                         const int* __restrict__ bsums,
                                                         int* __restrict__ offs, int N) {
    int t = threadIdx.x, lane = t & 63, w = t >> 6;
    int base = blockIdx.x * 1024 + t * 4;
    int v[4]; int s = 0;
    #pragma unroll
    for (int i = 0; i < 4; ++i) { int idx = base + i; v[i] = (idx < N) ? counts[idx] : 0; s += v[i]; }
    int x = s;
    #pragma unroll
    for (int d = 1; d < 64; d <<= 1) {
        int y = __shfl_up(x, d);
        if (lane >= d) x += y;
    }
    __shared__ int wtot[4];
    if (lane == 63) wtot[w] = x;
    __syncthreads();
    int wexc = 0;
    for (int i = 0; i < w; ++i) wexc += wtot[i];
    int run = (x - s) + wexc + bsums[blockIdx.x];
    #pragma unroll
    for (int i = 0; i < 4; ++i) {
        int idx = base + i;
        run += v[i];
        if (idx < N) offs[idx + 1] = run;
    }
    if (blockIdx.x == 0 && t == 0) offs[0] = 0;
}

// single int2 (src, eid) per slot: one 8B write per edge (write-amp fix)
__global__ __launch_bounds__(256) void scatter_kernel(
    const int* __restrict__ src, const int* __restrict__ dst,
    const int* __restrict__ offs, int* __restrict__ cursor,
    int2* __restrict__ csr_se, int E) {
    int e = blockIdx.x * 256 + threadIdx.x;
    if (e >= E) return;
    int d = dst[e];
    int pos = offs[d] + atomicAdd(&cursor[d], 1);
    csr_se[pos] = make_int2(src[e], e);
}

// canonical order: sort each dst-segment by eid (one wave per node, rank sort)
__global__ __launch_bounds__(256) void sort_segments_kernel(
    int2* __restrict__ csr_se, const int* __restrict__ offs, int N)
{
    int t = threadIdx.x;
    int lane = t & 63;
    int node = blockIdx.x * 4 + (t >> 6);
    if (node >= N) return;
    int off = offs[node];
    int deg = offs[node + 1] - off;
    if (deg <= 1) return;
    if (deg <= 64) {
        int key = 0x7FFFFFFF, val = 0;
        if (lane < deg) { int2 se = csr_se[off + lane]; key = se.y; val = se.x; }
        int rank = 0;
        #pragma unroll
        for (int i = 0; i < 64; ++i) {
            int ki = __shfl(key, i);
            if (ki < key) rank++;            // eids unique -> permutation
        }
        if (lane < deg) csr_se[off + rank] = make_int2(val, key);
    } else if (lane == 0) {
        for (int a = 1; a < deg; ++a) {
            int2 kv = csr_se[off + a];
            int b = a - 1;
            while (b >= 0 && csr_se[off + b].y > kv.y) {
                csr_se[off + b + 1] = csr_se[off + b];
                b--;
            }
            csr_se[off + b + 1] = kv;
        }
    }
}

// ---------------- per-layer kernels ----------------
// node_gemm v3: 64-row tile; lane=(row-slot, col-quad); LDS x broadcast + W float4.
#define XSTRIDE 68
__global__ __launch_bounds__(256) void node_gemm_kernel(
    const float* __restrict__ hin,
    const float* __restrict__ Wl, const float* __restrict__ bl,
    const float* __restrict__ Wr, const float* __restrict__ br,
    float* __restrict__ xl, float* __restrict__ xr, int nrows)
{
    __shared__ float sWl[4096];
    __shared__ float sWr[4096];
    __shared__ float sX[64 * XSTRIDE];
    int t = threadIdx.x;
    {
        float4* dl = (float4*)sWl; const float4* sl = (const float4*)Wl;
        float4* dr = (float4*)sWr; const float4* sr = (const float4*)Wr;
        for (int i = t; i < 1024; i += 256) { dl[i] = sl[i]; dr[i] = sr[i]; }
    }
    int row0 = blockIdx.x * 64;
    for (int i = t; i < 1024; i += 256) {
        int rr = i >> 4;
        int cc = (i & 15) << 2;
        int row = row0 + rr;
        float4 v = make_float4(0.f, 0.f, 0.f, 0.f);
        if (row < nrows) v = *(const float4*)(hin + (size_t)row * 64 + cc);
        *(float4*)(&sX[rr * XSTRIDE + cc]) = v;
    }
    __syncthreads();

    int lane = t & 63;
    int w = t >> 6;
    int rs = lane >> 4;
    int c4 = lane & 15;
    float4 bl4 = *(const float4*)(bl + c4 * 4);
    float4 br4 = *(const float4*)(br + c4 * 4);

    #pragma unroll
    for (int g = 0; g < 4; ++g) {
        int rloc = w * 16 + g * 4 + rs;
        int row = row0 + rloc;
        float4 al = {0.f, 0.f, 0.f, 0.f};
        float4 ar = {0.f, 0.f, 0.f, 0.f};
        const float* xrow = &sX[rloc * XSTRIDE];
        #pragma unroll 4
        for (int k = 0; k < 64; ++k) {
            float xk = xrow[k];
            float4 wl4 = *(const float4*)(&sWl[k * 64 + c4 * 4]);
            float4 wr4 = *(const float4*)(&sWr[k * 64 + c4 * 4]);
            al.x += xk * wl4.x; al.y += xk * wl4.y;
            al.z += xk * wl4.z; al.w += xk * wl4.w;
            ar.x += xk * wr4.x; ar.y += xk * wr4.y;
            ar.z += xk * wr4.z; ar.w += xk * wr4.w;
        }
        if (row < nrows) {
            float4 ol, orr;
            ol.x = al.x + bl4.x; ol.y = al.y + bl4.y;
            ol.z = al.z + bl4.z; ol.w = al.w + bl4.w;
            orr.x = ar.x + br4.x; orr.y = ar.y + br4.y;
            orr.z = ar.z + br4.z; orr.w = ar.w + br4.w;
            *(float4*)(xl + (size_t)row * 64 + c4 * 4) = ol;
            *(float4*)(xr + (size_t)row * 64 + c4 * 4) = orr;
        }
    }
}

// fused edge-score + online-softmax aggregate: one WAVE per node, lane = channel.
// Serial over in-edges in canonical (eid-sorted) order -> deterministic.
__global__ __launch_bounds__(256) void fused_attn_kernel(
    const float* __restrict__ xl, const float* __restrict__ xr,
    const float* __restrict__ ea,
    const int2* __restrict__ csr_se, const int* __restrict__ offs,
    const float* __restrict__ We, const float* __restrict__ att,
    const float* __restrict__ bias, float* __restrict__ hout, int N)
{
    int t = threadIdx.x;
    int lane = t & 63;
    int node = blockIdx.x * 4 + (t >> 6);
    if (node >= N) return;

    // per-lane We column in registers (no LDS): wv[k] = We[k][lane]
    float wv[16];
    #pragma unroll
    for (int k = 0; k < 16; ++k) wv[k] = We[k * 64 + lane];
    float attc = att[lane];          // att[h][cw] flattened == lane
    float bc   = bias[lane];
    float xrc  = xr[(size_t)node * 64 + lane];

    int off = offs[node];
    int deg = offs[node + 1] - off;

    float m = -FLT_MAX, s = 0.f, acc = 0.f;
    for (int j = 0; j < deg; ++j) {
        int2 se = csr_se[off + j];                    // wave-uniform -> s_load
        const float4* ap = (const float4*)(ea + (size_t)se.y * 16);
        float4 a0 = ap[0], a1 = ap[1], a2 = ap[2], a3 = ap[3];
        float xlc = xl[(size_t)se.x * 64 + lane];     // coalesced 256B/wave
        float ef = a0.x * wv[0]  + a0.y * wv[1]  + a0.z * wv[2]  + a0.w * wv[3]
                 + a1.x * wv[4]  + a1.y * wv[5]  + a1.z * wv[6]  + a1.w * wv[7]
                 + a2.x * wv[8]  + a2.y * wv[9]  + a2.z * wv[10] + a2.w * wv[11]
                 + a3.x * wv[12] + a3.y * wv[13] + a3.z * wv[14] + a3.w * wv[15];
        float mm = xlc + xrc + ef;
        mm = (mm >= 0.f) ? mm : NEG_SLOPE * mm;
        float sc = mm * attc;
        // reduce over the 16 channels of this head (DPP-friendly strides)
        sc += __shfl_xor(sc, 1);
        sc += __shfl_xor(sc, 2);
        sc += __shfl_xor(sc, 4);
        sc += __shfl_xor(sc, 8);
        // branchless online softmax (deterministic serial order)
        float nm = fmaxf(m, sc);
        float scale = __expf(m - nm);                 // 0 on first iter
        float p = __expf(sc - nm);
        s   = s * scale + p;
        acc = acc * scale + p * xlc;
        m = nm;
    }

    float v = (deg > 0) ? (acc / s) : 0.f;
    v += bc;
    hout[(size_t)node * 64 + lane] = fmaxf(v, 0.f);
}

extern "C" void kernel_launch(void* const* d_in, const int* in_sizes, int n_in,
                              void* d_out, int out_size, void* d_ws, size_t ws_size,
                              hipStream_t stream) {
    const float* x    = (const float*)d_in[0];
    const int*   eidx = (const int*)d_in[1];
    const float* ea   = (const float*)d_in[2];
    const float* Wl   = (const float*)d_in[3];
    const float* bl   = (const float*)d_in[4];
    const float* Wr   = (const float*)d_in[5];
    const float* br   = (const float*)d_in[6];
    const float* We   = (const float*)d_in[7];
    const float* att  = (const float*)d_in[8];
    const float* bias = (const float*)d_in[9];
    float* out = (float*)d_out;

    const int N = in_sizes[0] / 64;
    const int E = in_sizes[1] / 2;
    const int* src = eidx;
    const int* dst = eidx + E;

    float* ws = (float*)d_ws;
    float* xl      = ws;                               // N*64
    float* xr      = xl + (size_t)N * 64;              // N*64
    float* h_tmp   = xr + (size_t)N * 64;              // N*64
    int* counts    = (int*)(h_tmp + (size_t)N * 64);   // N
    int* cursor    = counts + N;                       // N
    int* offs      = cursor + N;                       // N+1
    int* bsums     = offs + N + 1;                     // ~64
    int2* csr_se   = (int2*)(bsums + 64);              // E int2 (8B-aligned: offset even)

    dim3 blk(256);
    int g_n    = (N + 255) / 256;
    int g_e    = (E + 255) / 256;
    int g_gemm = (N + 63) / 64;
    int g_node = (N + 3) / 4;
    int NB     = (N + 1023) / 1024;   // 49 for N=50000 (<= 64)

    // CSR over dst, canonical eid order (edge_index is layer-invariant)
    zero_kernel<<<g_n, blk, 0, stream>>>(counts, cursor, N);
    count_kernel<<<g_e, blk, 0, stream>>>(dst, counts, E);
    scan_bsums_kernel<<<NB, blk, 0, stream>>>(counts, bsums, N);
    scan_bscan_kernel<<<1, 64, 0, stream>>>(bsums, NB);
    scan_final_kernel<<<NB, blk, 0, stream>>>(counts, bsums, offs, N);
    scatter_kernel<<<g_e, blk, 0, stream>>>(src, dst, offs, cursor, csr_se, E);
    sort_segments_kernel<<<g_node, blk, 0, stream>>>(csr_se, offs, N);

    const float* hin = x;
    for (int l = 0; l < 3; ++l) {
        float* hout = (l == 2) ? out : h_tmp;
        node_gemm_kernel<<<g_gemm, blk, 0, stream>>>(hin, Wl + (size_t)l * 4096, bl + l * 64,
                                                     Wr + (size_t)l * 4096, br + l * 64, xl, xr, N);
        fused_attn_kernel<<<g_node, blk, 0, stream>>>(xl, xr, ea, csr_se, offs,
                                                      We + (size_t)l * 1024, att + l * 64,
                                                      bias + l * 64, hout, N);
        hin = hout;
    }
}

// Round 16
// 527.150 us; speedup vs baseline: 1.1872x; 1.1872x over previous
//
#include <hip/hip_runtime.h>
#include <cfloat>

#define NEG_SLOPE 0.2f

// ---------------- CSR build ----------------
__global__ __launch_bounds__(256) void zero_kernel(int* __restrict__ counts,
                                                   int* __restrict__ cursor, int n) {
    int gid = blockIdx.x * 256 + threadIdx.x;
    if (gid < n) { counts[gid] = 0; cursor[gid] = 0; }
}

__global__ __launch_bounds__(256) void count_kernel(const int* __restrict__ dst,
                                                    int* __restrict__ counts, int E) {
    int e = blockIdx.x * 256 + threadIdx.x;
    if (e < E) atomicAdd(&counts[dst[e]], 1);
}

// ---- hierarchical scan: 1024 elements per block ----
__global__ __launch_bounds__(256) void scan_bsums_kernel(const int* __restrict__ counts,
                                                         int* __restrict__ bsums, int N) {
    int t = threadIdx.x;
    int base = blockIdx.x * 1024 + t * 4;
    int s = 0;
    #pragma unroll
    for (int i = 0; i < 4; ++i) { int idx = base + i; if (idx < N) s += counts[idx]; }
    #pragma unroll
    for (int d = 1; d < 64; d <<= 1) s += __shfl_xor(s, d);
    __shared__ int ws[4];
    if ((t & 63) == 0) ws[t >> 6] = s;
    __syncthreads();
    if (t == 0) bsums[blockIdx.x] = ws[0] + ws[1] + ws[2] + ws[3];
}

__global__ __launch_bounds__(64) void scan_bscan_kernel(int* __restrict__ bsums, int NB) {
    int t = threadIdx.x;
    int v = (t < NB) ? bsums[t] : 0;
    int x = v;
    #pragma unroll
    for (int d = 1; d < 64; d <<= 1) {
        int y = __shfl_up(x, d);
        if (t >= d) x += y;
    }
    if (t < NB) bsums[t] = x - v;   // exclusive
}

__global__ __launch_bounds__(256) void scan_final_kernel(const int* __restrict__ counts,
                                                         const int* __restrict__ bsums,
                                                         int* __restrict__ offs, int N) {
    int t = threadIdx.x, lane = t & 63, w = t >> 6;
    int base = blockIdx.x * 1024 + t * 4;
    int v[4]; int s = 0;
    #pragma unroll
    for (int i = 0; i < 4; ++i) { int idx = base + i; v[i] = (idx < N) ? counts[idx] : 0; s += v[i]; }
    int x = s;
    #pragma unroll
    for (int d = 1; d < 64; d <<= 1) {
        int y = __shfl_up(x, d);
        if (lane >= d) x += y;
    }
    __shared__ int wtot[4];
    if (lane == 63) wtot[w] = x;
    __syncthreads();
    int wexc = 0;
    for (int i = 0; i < w; ++i) wexc += wtot[i];
    int run = (x - s) + wexc + bsums[blockIdx.x];
    #pragma unroll
    for (int i = 0; i < 4; ++i) {
        int idx = base + i;
        run += v[i];
        if (idx < N) offs[idx + 1] = run;
    }
    if (blockIdx.x == 0 && t == 0) offs[0] = 0;
}

// single int4 (src, dst, eid, 0): ONE 16B write per edge (write-amp fix)
__global__ __launch_bounds__(256) void scatter_kernel(
    const int* __restrict__ src, const int* __restrict__ dst,
    const int* __restrict__ offs, int* __restrict__ cursor,
    int4* __restrict__ csr, int E) {
    int e = blockIdx.x * 256 + threadIdx.x;
    if (e >= E) return;
    int d = dst[e];
    int pos = offs[d] + atomicAdd(&cursor[d], 1);
    csr[pos] = make_int4(src[e], d, e, 0);
}

// canonical order: sort each dst-segment by eid (one wave per node, rank sort)
__global__ __launch_bounds__(256) void sort_segments_kernel(
    int4* __restrict__ csr, const int* __restrict__ offs, int N)
{
    int t = threadIdx.x;
    int lane = t & 63;
    int node = blockIdx.x * 4 + (t >> 6);
    if (node >= N) return;
    int off = offs[node];
    int deg = offs[node + 1] - off;
    if (deg <= 1) return;
    if (deg <= 64) {
        int key = 0x7FFFFFFF; int4 kv = make_int4(0, 0, 0, 0);
        if (lane < deg) { kv = csr[off + lane]; key = kv.z; }
        int rank = 0;
        #pragma unroll
        for (int i = 0; i < 64; ++i) {
            int ki = __shfl(key, i);
            if (ki < key) rank++;            // eids unique -> permutation
        }
        if (lane < deg) csr[off + rank] = kv;
    } else if (lane == 0) {
        for (int a = 1; a < deg; ++a) {
            int4 kv = csr[off + a];
            int b = a - 1;
            while (b >= 0 && csr[off + b].z > kv.z) {
                csr[off + b + 1] = csr[off + b];
                b--;
            }
            csr[off + b + 1] = kv;
        }
    }
}

// permute ea rows into CSR order (one-time; edge_index is layer-invariant)
__global__ __launch_bounds__(256) void eaperm_kernel(
    const float* __restrict__ ea, const int4* __restrict__ csr,
    float* __restrict__ eaperm, int E)
{
    int gid = blockIdx.x * 256 + threadIdx.x;
    int pos = gid >> 2, q = gid & 3;
    if (pos >= E) return;
    int eid = csr[pos].z;
    *(float4*)(eaperm + (size_t)pos * 16 + q * 4) =
        *(const float4*)(ea + (size_t)eid * 16 + q * 4);
}

// ---------------- per-layer kernels ----------------
// node_gemm v3: 64-row tile; lane=(row-slot, col-quad); LDS x broadcast + W float4.
#define XSTRIDE 68
__global__ __launch_bounds__(256) void node_gemm_kernel(
    const float* __restrict__ hin,
    const float* __restrict__ Wl, const float* __restrict__ bl,
    const float* __restrict__ Wr, const float* __restrict__ br,
    float* __restrict__ xl, float* __restrict__ xr, int nrows)
{
    __shared__ float sWl[4096];
    __shared__ float sWr[4096];
    __shared__ float sX[64 * XSTRIDE];
    int t = threadIdx.x;
    {
        float4* dl = (float4*)sWl; const float4* sl = (const float4*)Wl;
        float4* dr = (float4*)sWr; const float4* sr = (const float4*)Wr;
        for (int i = t; i < 1024; i += 256) { dl[i] = sl[i]; dr[i] = sr[i]; }
    }
    int row0 = blockIdx.x * 64;
    for (int i = t; i < 1024; i += 256) {
        int rr = i >> 4;
        int cc = (i & 15) << 2;
        int row = row0 + rr;
        float4 v = make_float4(0.f, 0.f, 0.f, 0.f);
        if (row < nrows) v = *(const float4*)(hin + (size_t)row * 64 + cc);
        *(float4*)(&sX[rr * XSTRIDE + cc]) = v;
    }
    __syncthreads();

    int lane = t & 63;
    int w = t >> 6;
    int rs = lane >> 4;
    int c4 = lane & 15;
    float4 bl4 = *(const float4*)(bl + c4 * 4);
    float4 br4 = *(const float4*)(br + c4 * 4);

    #pragma unroll
    for (int g = 0; g < 4; ++g) {
        int rloc = w * 16 + g * 4 + rs;
        int row = row0 + rloc;
        float4 al = {0.f, 0.f, 0.f, 0.f};
        float4 ar = {0.f, 0.f, 0.f, 0.f};
        const float* xrow = &sX[rloc * XSTRIDE];
        #pragma unroll 4
        for (int k = 0; k < 64; ++k) {
            float xk = xrow[k];
            float4 wl4 = *(const float4*)(&sWl[k * 64 + c4 * 4]);
            float4 wr4 = *(const float4*)(&sWr[k * 64 + c4 * 4]);
            al.x += xk * wl4.x; al.y += xk * wl4.y;
            al.z += xk * wl4.z; al.w += xk * wl4.w;
            ar.x += xk * wr4.x; ar.y += xk * wr4.y;
            ar.z += xk * wr4.z; ar.w += xk * wr4.w;
        }
        if (row < nrows) {
            float4 ol, orr;
            ol.x = al.x + bl4.x; ol.y = al.y + bl4.y;
            ol.z = al.z + bl4.z; ol.w = al.w + bl4.w;
            orr.x = ar.x + br4.x; orr.y = ar.y + br4.y;
            orr.z = ar.z + br4.z; orr.w = ar.w + br4.w;
            *(float4*)(xl + (size_t)row * 64 + c4 * 4) = ol;
            *(float4*)(xr + (size_t)row * 64 + c4 * 4) = orr;
        }
    }
}

// one thread per (CSR position, head); ea from sequential eaperm (or eid fallback)
__global__ __launch_bounds__(256) void edge_score_kernel(
    const float* __restrict__ xl, const float* __restrict__ xr,
    const float* __restrict__ ea, const float* __restrict__ eaperm, int use_perm,
    const int4* __restrict__ csr,
    const float* __restrict__ We, const float* __restrict__ att,
    float* __restrict__ score_csr, int E)
{
    __shared__ float sWe[1024];   // 16 x 64
    __shared__ float sAtt[64];    // 4 x 16
    int t = threadIdx.x;
    for (int i = t; i < 1024; i += 256) sWe[i] = We[i];
    if (t < 64) sAtt[t] = att[t];
    __syncthreads();
    int gid = blockIdx.x * 256 + t;
    int pos = gid >> 2, h = gid & 3;
    if (pos >= E) return;
    int4 se = csr[pos];
    int s = se.x, d = se.y;
    const float4* eap = use_perm
        ? (const float4*)(eaperm + (size_t)pos * 16)
        : (const float4*)(ea + (size_t)se.z * 16);
    float4 a0 = eap[0], a1 = eap[1], a2 = eap[2], a3 = eap[3];
    float av[16] = {a0.x, a0.y, a0.z, a0.w, a1.x, a1.y, a1.z, a1.w,
                    a2.x, a2.y, a2.z, a2.w, a3.x, a3.y, a3.z, a3.w};
    const float4* xls = (const float4*)(xl + (size_t)s * 64 + h * 16);
    const float4* xrd = (const float4*)(xr + (size_t)d * 64 + h * 16);
    float4 vl0 = xls[0], vl1 = xls[1], vl2 = xls[2], vl3 = xls[3];
    float4 vr0 = xrd[0], vr1 = xrd[1], vr2 = xrd[2], vr3 = xrd[3];

    float ef[16];
    #pragma unroll
    for (int c = 0; c < 16; ++c) ef[c] = 0.f;
    #pragma unroll
    for (int k = 0; k < 16; ++k) {
        float a = av[k];
        const float* wrow = &sWe[k * 64 + h * 16];
        #pragma unroll
        for (int c = 0; c < 16; ++c) ef[c] += a * wrow[c];
    }

    float lv[16] = {vl0.x, vl0.y, vl0.z, vl0.w, vl1.x, vl1.y, vl1.z, vl1.w,
                    vl2.x, vl2.y, vl2.z, vl2.w, vl3.x, vl3.y, vl3.z, vl3.w};
    float rv[16] = {vr0.x, vr0.y, vr0.z, vr0.w, vr1.x, vr1.y, vr1.z, vr1.w,
                    vr2.x, vr2.y, vr2.z, vr2.w, vr3.x, vr3.y, vr3.z, vr3.w};
    float sc0 = 0.f, sc1 = 0.f, sc2 = 0.f, sc3 = 0.f;
    #pragma unroll
    for (int c = 0; c < 16; c += 4) {
        float m0 = lv[c] + rv[c] + ef[c];
        float m1 = lv[c+1] + rv[c+1] + ef[c+1];
        float m2 = lv[c+2] + rv[c+2] + ef[c+2];
        float m3 = lv[c+3] + rv[c+3] + ef[c+3];
        m0 = (m0 >= 0.f) ? m0 : NEG_SLOPE * m0;
        m1 = (m1 >= 0.f) ? m1 : NEG_SLOPE * m1;
        m2 = (m2 >= 0.f) ? m2 : NEG_SLOPE * m2;
        m3 = (m3 >= 0.f) ? m3 : NEG_SLOPE * m3;
        sc0 += m0 * sAtt[h * 16 + c];
        sc1 += m1 * sAtt[h * 16 + c + 1];
        sc2 += m2 * sAtt[h * 16 + c + 2];
        sc3 += m3 * sAtt[h * 16 + c + 3];
    }
    score_csr[gid] = (sc0 + sc1) + (sc2 + sc3);
}

// one WAVE per node; lane = (edge-slot eg 0..3, channel-quad k 0..15, head = k>>2)
__global__ __launch_bounds__(256) void node_pass_kernel(
    const float* __restrict__ score_csr, const float* __restrict__ xl,
    const int4* __restrict__ csr,
    const int* __restrict__ offs, const float* __restrict__ bias,
    float* __restrict__ hout, int N)
{
    int t = threadIdx.x;
    int lane = t & 63;
    int node = blockIdx.x * 4 + (t >> 6);
    if (node >= N) return;
    int eg = lane >> 4;          // edge slot
    int k  = lane & 15;          // channel quad; head = k>>2
    int h  = k >> 2;
    int off = offs[node];
    int deg = offs[node + 1] - off;

    if (deg == 0) {
        if (eg == 0) {
            float4 b = *(const float4*)(bias + k * 4);
            float4 o;
            o.x = fmaxf(b.x, 0.f); o.y = fmaxf(b.y, 0.f);
            o.z = fmaxf(b.z, 0.f); o.w = fmaxf(b.w, 0.f);
            *(float4*)(hout + (size_t)node * 64 + k * 4) = o;
        }
        return;
    }

    // pass 1: head max (exact, order-free)
    float mx = -FLT_MAX;
    for (int j0 = 0; j0 < deg; j0 += 4) {
        int j = j0 + eg;
        if (j < deg) {
            float sc = score_csr[(size_t)(off + j) * 4 + h];
            mx = fmaxf(mx, sc);
        }
    }
    mx = fmaxf(mx, __shfl_xor(mx, 16));
    mx = fmaxf(mx, __shfl_xor(mx, 32));

    // pass 2: 4 edges per iteration, float4 FMA payload
    float4 acc = {0.f, 0.f, 0.f, 0.f};
    float sSum = 0.f;
    for (int j0 = 0; j0 < deg; j0 += 4) {
        int j = j0 + eg;
        int jj = (j < deg) ? j : deg - 1;
        int pos = off + jj;
        int s = csr[pos].x;
        float sc = score_csr[(size_t)pos * 4 + h];
        float ex = (j < deg) ? __expf(sc - mx) : 0.f;
        float4 v = *(const float4*)(xl + (size_t)s * 64 + k * 4);
        acc.x += ex * v.x; acc.y += ex * v.y;
        acc.z += ex * v.z; acc.w += ex * v.w;
        sSum += ex;
    }

    // fixed-grouping butterfly reduce (deterministic)
    acc.x += __shfl_xor(acc.x, 16); acc.y += __shfl_xor(acc.y, 16);
    acc.z += __shfl_xor(acc.z, 16); acc.w += __shfl_xor(acc.w, 16);
    sSum  += __shfl_xor(sSum, 16);
    acc.x += __shfl_xor(acc.x, 32); acc.y += __shfl_xor(acc.y, 32);
    acc.z += __shfl_xor(acc.z, 32); acc.w += __shfl_xor(acc.w, 32);
    sSum  += __shfl_xor(sSum, 32);

    if (eg == 0) {
        float inv = 1.f / sSum;
        float4 b = *(const float4*)(bias + k * 4);
        float4 o;
        o.x = fmaxf(acc.x * inv + b.x, 0.f);
        o.y = fmaxf(acc.y * inv + b.y, 0.f);
        o.z = fmaxf(acc.z * inv + b.z, 0.f);
        o.w = fmaxf(acc.w * inv + b.w, 0.f);
        *(float4*)(hout + (size_t)node * 64 + k * 4) = o;
    }
}

extern "C" void kernel_launch(void* const* d_in, const int* in_sizes, int n_in,
                              void* d_out, int out_size, void* d_ws, size_t ws_size,
                              hipStream_t stream) {
    const float* x    = (const float*)d_in[0];
    const int*   eidx = (const int*)d_in[1];
    const float* ea   = (const float*)d_in[2];
    const float* Wl   = (const float*)d_in[3];
    const float* bl   = (const float*)d_in[4];
    const float* Wr   = (const float*)d_in[5];
    const float* br   = (const float*)d_in[6];
    const float* We   = (const float*)d_in[7];
    const float* att  = (const float*)d_in[8];
    const float* bias = (const float*)d_in[9];
    float* out = (float*)d_out;

    const int N = in_sizes[0] / 64;
    const int E = in_sizes[1] / 2;
    const int* src = eidx;
    const int* dst = eidx + E;

    float* ws = (float*)d_ws;
    float* xl      = ws;                               // N*64
    float* xr      = xl + (size_t)N * 64;              // N*64
    float* score   = xr + (size_t)N * 64;              // E*4
    float* h_tmp   = score + (size_t)E * 4;            // N*64
    int* counts    = (int*)(h_tmp + (size_t)N * 64);   // N
    int* cursor    = counts + N;                       // N
    int* offs      = cursor + N;                       // N+1
    int* bsums     = offs + N + 1;                     // 64
    uintptr_t p    = (uintptr_t)(bsums + 64);
    p = (p + 15) & ~(uintptr_t)15;
    int4* csr      = (int4*)p;                         // E int4 (16B aligned)
    float* eaperm  = (float*)(csr + E);                // E*16 (optional)

    size_t need_base = (uintptr_t)(eaperm) - (uintptr_t)d_ws;
    size_t need_perm = need_base + (size_t)E * 16 * sizeof(float);
    int use_perm = (ws_size >= need_perm) ? 1 : 0;

    dim3 blk(256);
    int g_n    = (N + 255) / 256;
    int g_e    = (E + 255) / 256;
    int g_eh   = (E * 4 + 255) / 256;
    int g_gemm = (N + 63) / 64;
    int g_node = (N + 3) / 4;
    int NB     = (N + 1023) / 1024;   // 49 for N=50000 (<= 64)

    // CSR over dst, canonical eid order (edge_index is layer-invariant)
    zero_kernel<<<g_n, blk, 0, stream>>>(counts, cursor, N);
    count_kernel<<<g_e, blk, 0, stream>>>(dst, counts, E);
    scan_bsums_kernel<<<NB, blk, 0, stream>>>(counts, bsums, N);
    scan_bscan_kernel<<<1, 64, 0, stream>>>(bsums, NB);
    scan_final_kernel<<<NB, blk, 0, stream>>>(counts, bsums, offs, N);
    scatter_kernel<<<g_e, blk, 0, stream>>>(src, dst, offs, cursor, csr, E);
    sort_segments_kernel<<<g_node, blk, 0, stream>>>(csr, offs, N);
    if (use_perm)
        eaperm_kernel<<<g_eh, blk, 0, stream>>>(ea, csr, eaperm, E);

    const float* hin = x;
    for (int l = 0; l < 3; ++l) {
        float* hout = (l == 2) ? out : h_tmp;
        node_gemm_kernel<<<g_gemm, blk, 0, stream>>>(hin, Wl + (size_t)l * 4096, bl + l * 64,
                                                     Wr + (size_t)l * 4096, br + l * 64, xl, xr, N);
        edge_score_kernel<<<g_eh, blk, 0, stream>>>(xl, xr, ea, eaperm, use_perm, csr,
                                                    We + (size_t)l * 1024, att + l * 64,
                                                    score, E);
        node_pass_kernel<<<g_node, blk, 0, stream>>>(score, xl, csr, offs,
                                                     bias + l * 64, hout, N);
        hin = hout;
    }
}

// Round 17
// 518.934 us; speedup vs baseline: 1.2060x; 1.0158x over previous
//
#include <hip/hip_runtime.h>
#include <cfloat>

#define NEG_SLOPE 0.2f

// ---------------- CSR build ----------------
__global__ __launch_bounds__(256) void zero_kernel(int* __restrict__ counts,
                                                   int* __restrict__ cursor, int n) {
    int gid = blockIdx.x * 256 + threadIdx.x;
    if (gid < n) { counts[gid] = 0; cursor[gid] = 0; }
}

__global__ __launch_bounds__(256) void count_kernel(const int* __restrict__ dst,
                                                    int* __restrict__ counts, int E) {
    int e = blockIdx.x * 256 + threadIdx.x;
    if (e < E) atomicAdd(&counts[dst[e]], 1);
}

// ---- hierarchical scan: 1024 elements per block ----
__global__ __launch_bounds__(256) void scan_bsums_kernel(const int* __restrict__ counts,
                                                         int* __restrict__ bsums, int N) {
    int t = threadIdx.x;
    int base = blockIdx.x * 1024 + t * 4;
    int s = 0;
    #pragma unroll
    for (int i = 0; i < 4; ++i) { int idx = base + i; if (idx < N) s += counts[idx]; }
    #pragma unroll
    for (int d = 1; d < 64; d <<= 1) s += __shfl_xor(s, d);
    __shared__ int ws[4];
    if ((t & 63) == 0) ws[t >> 6] = s;
    __syncthreads();
    if (t == 0) bsums[blockIdx.x] = ws[0] + ws[1] + ws[2] + ws[3];
}

__global__ __launch_bounds__(64) void scan_bscan_kernel(int* __restrict__ bsums, int NB) {
    int t = threadIdx.x;
    int v = (t < NB) ? bsums[t] : 0;
    int x = v;
    #pragma unroll
    for (int d = 1; d < 64; d <<= 1) {
        int y = __shfl_up(x, d);
        if (t >= d) x += y;
    }
    if (t < NB) bsums[t] = x - v;   // exclusive
}

__global__ __launch_bounds__(256) void scan_final_kernel(const int* __restrict__ counts,
                                                         const int* __restrict__ bsums,
                                                         int* __restrict__ offs, int N) {
    int t = threadIdx.x, lane = t & 63, w = t >> 6;
    int base = blockIdx.x * 1024 + t * 4;
    int v[4]; int s = 0;
    #pragma unroll
    for (int i = 0; i < 4; ++i) { int idx = base + i; v[i] = (idx < N) ? counts[idx] : 0; s += v[i]; }
    int x = s;
    #pragma unroll
    for (int d = 1; d < 64; d <<= 1) {
        int y = __shfl_up(x, d);
        if (lane >= d) x += y;
    }
    __shared__ int wtot[4];
    if (lane == 63) wtot[w] = x;
    __syncthreads();
    int wexc = 0;
    for (int i = 0; i < w; ++i) wexc += wtot[i];
    int run = (x - s) + wexc + bsums[blockIdx.x];
    #pragma unroll
    for (int i = 0; i < 4; ++i) {
        int idx = base + i;
        run += v[i];
        if (idx < N) offs[idx + 1] = run;
    }
    if (blockIdx.x == 0 && t == 0) offs[0] = 0;
}

// 4 edges per thread: 4 independent {read, atomic, write} chains -> 4x MLP
__global__ __launch_bounds__(256) void scatter_kernel(
    const int* __restrict__ src, const int* __restrict__ dst,
    const int* __restrict__ offs, int* __restrict__ cursor,
    int4* __restrict__ csr, int E) {
    int base = (blockIdx.x * 256 + threadIdx.x) * 4;
    if (base >= E) return;
    int n = E - base; if (n > 4) n = 4;
    int s0[4], d0[4], p0[4];
    #pragma unroll
    for (int i = 0; i < 4; ++i) {
        if (i < n) { s0[i] = src[base + i]; d0[i] = dst[base + i]; }
    }
    #pragma unroll
    for (int i = 0; i < 4; ++i) {
        if (i < n) p0[i] = offs[d0[i]] + atomicAdd(&cursor[d0[i]], 1);
    }
    #pragma unroll
    for (int i = 0; i < 4; ++i) {
        if (i < n) csr[p0[i]] = make_int4(s0[i], d0[i], base + i, 0);
    }
}

// canonical order: sort each dst-segment by eid (one wave per node, rank sort)
__global__ __launch_bounds__(256) void sort_segments_kernel(
    int4* __restrict__ csr, const int* __restrict__ offs, int N)
{
    int t = threadIdx.x;
    int lane = t & 63;
    int node = blockIdx.x * 4 + (t >> 6);
    if (node >= N) return;
    int off = offs[node];
    int deg = offs[node + 1] - off;
    if (deg <= 1) return;
    if (deg <= 64) {
        int key = 0x7FFFFFFF; int4 kv = make_int4(0, 0, 0, 0);
        if (lane < deg) { kv = csr[off + lane]; key = kv.z; }
        int rank = 0;
        #pragma unroll
        for (int i = 0; i < 64; ++i) {
            int ki = __shfl(key, i);
            if (ki < key) rank++;            // eids unique -> permutation
        }
        if (lane < deg) csr[off + rank] = kv;
    } else if (lane == 0) {
        for (int a = 1; a < deg; ++a) {
            int4 kv = csr[off + a];
            int b = a - 1;
            while (b >= 0 && csr[off + b].z > kv.z) {
                csr[off + b + 1] = csr[off + b];
                b--;
            }
            csr[off + b + 1] = kv;
        }
    }
}

// ---------------- per-layer kernels ----------------
// node_gemm v3: 64-row tile; lane=(row-slot, col-quad); LDS x broadcast + W float4.
#define XSTRIDE 68
__global__ __launch_bounds__(256) void node_gemm_kernel(
    const float* __restrict__ hin,
    const float* __restrict__ Wl, const float* __restrict__ bl,
    const float* __restrict__ Wr, const float* __restrict__ br,
    float* __restrict__ xl, float* __restrict__ xr, int nrows)
{
    __shared__ float sWl[4096];
    __shared__ float sWr[4096];
    __shared__ float sX[64 * XSTRIDE];
    int t = threadIdx.x;
    {
        float4* dl = (float4*)sWl; const float4* sl = (const float4*)Wl;
        float4* dr = (float4*)sWr; const float4* sr = (const float4*)Wr;
        for (int i = t; i < 1024; i += 256) { dl[i] = sl[i]; dr[i] = sr[i]; }
    }
    int row0 = blockIdx.x * 64;
    for (int i = t; i < 1024; i += 256) {
        int rr = i >> 4;
        int cc = (i & 15) << 2;
        int row = row0 + rr;
        float4 v = make_float4(0.f, 0.f, 0.f, 0.f);
        if (row < nrows) v = *(const float4*)(hin + (size_t)row * 64 + cc);
        *(float4*)(&sX[rr * XSTRIDE + cc]) = v;
    }
    __syncthreads();

    int lane = t & 63;
    int w = t >> 6;
    int rs = lane >> 4;
    int c4 = lane & 15;
    float4 bl4 = *(const float4*)(bl + c4 * 4);
    float4 br4 = *(const float4*)(br + c4 * 4);

    #pragma unroll
    for (int g = 0; g < 4; ++g) {
        int rloc = w * 16 + g * 4 + rs;
        int row = row0 + rloc;
        float4 al = {0.f, 0.f, 0.f, 0.f};
        float4 ar = {0.f, 0.f, 0.f, 0.f};
        const float* xrow = &sX[rloc * XSTRIDE];
        #pragma unroll 4
        for (int k = 0; k < 64; ++k) {
            float xk = xrow[k];
            float4 wl4 = *(const float4*)(&sWl[k * 64 + c4 * 4]);
            float4 wr4 = *(const float4*)(&sWr[k * 64 + c4 * 4]);
            al.x += xk * wl4.x; al.y += xk * wl4.y;
            al.z += xk * wl4.z; al.w += xk * wl4.w;
            ar.x += xk * wr4.x; ar.y += xk * wr4.y;
            ar.z += xk * wr4.z; ar.w += xk * wr4.w;
        }
        if (row < nrows) {
            float4 ol, orr;
            ol.x = al.x + bl4.x; ol.y = al.y + bl4.y;
            ol.z = al.z + bl4.z; ol.w = al.w + bl4.w;
            orr.x = ar.x + br4.x; orr.y = ar.y + br4.y;
            orr.z = ar.z + br4.z; orr.w = ar.w + br4.w;
            *(float4*)(xl + (size_t)row * 64 + c4 * 4) = ol;
            *(float4*)(xr + (size_t)row * 64 + c4 * 4) = orr;
        }
    }
}

// one thread per (CSR position, head); ea read directly via eid (64B rows: random
// full-coverage reads fetch the same bytes as sequential — no permute needed)
__global__ __launch_bounds__(256) void edge_score_kernel(
    const float* __restrict__ xl, const float* __restrict__ xr,
    const float* __restrict__ ea,
    const int4* __restrict__ csr,
    const float* __restrict__ We, const float* __restrict__ att,
    float* __restrict__ score_csr, int E)
{
    __shared__ float sWe[1024];   // 16 x 64
    __shared__ float sAtt[64];    // 4 x 16
    int t = threadIdx.x;
    for (int i = t; i < 1024; i += 256) sWe[i] = We[i];
    if (t < 64) sAtt[t] = att[t];
    __syncthreads();
    int gid = blockIdx.x * 256 + t;
    int pos = gid >> 2, h = gid & 3;
    if (pos >= E) return;
    int4 se = csr[pos];
    int s = se.x, d = se.y;
    const float4* eap = (const float4*)(ea + (size_t)se.z * 16);
    float4 a0 = eap[0], a1 = eap[1], a2 = eap[2], a3 = eap[3];
    float av[16] = {a0.x, a0.y, a0.z, a0.w, a1.x, a1.y, a1.z, a1.w,
                    a2.x, a2.y, a2.z, a2.w, a3.x, a3.y, a3.z, a3.w};
    const float4* xls = (const float4*)(xl + (size_t)s * 64 + h * 16);
    const float4* xrd = (const float4*)(xr + (size_t)d * 64 + h * 16);
    float4 vl0 = xls[0], vl1 = xls[1], vl2 = xls[2], vl3 = xls[3];
    float4 vr0 = xrd[0], vr1 = xrd[1], vr2 = xrd[2], vr3 = xrd[3];

    float ef[16];
    #pragma unroll
    for (int c = 0; c < 16; ++c) ef[c] = 0.f;
    #pragma unroll
    for (int k = 0; k < 16; ++k) {
        float a = av[k];
        const float* wrow = &sWe[k * 64 + h * 16];
        #pragma unroll
        for (int c = 0; c < 16; ++c) ef[c] += a * wrow[c];
    }

    float lv[16] = {vl0.x, vl0.y, vl0.z, vl0.w, vl1.x, vl1.y, vl1.z, vl1.w,
                    vl2.x, vl2.y, vl2.z, vl2.w, vl3.x, vl3.y, vl3.z, vl3.w};
    float rv[16] = {vr0.x, vr0.y, vr0.z, vr0.w, vr1.x, vr1.y, vr1.z, vr1.w,
                    vr2.x, vr2.y, vr2.z, vr2.w, vr3.x, vr3.y, vr3.z, vr3.w};
    float sc0 = 0.f, sc1 = 0.f, sc2 = 0.f, sc3 = 0.f;
    #pragma unroll
    for (int c = 0; c < 16; c += 4) {
        float m0 = lv[c] + rv[c] + ef[c];
        float m1 = lv[c+1] + rv[c+1] + ef[c+1];
        float m2 = lv[c+2] + rv[c+2] + ef[c+2];
        float m3 = lv[c+3] + rv[c+3] + ef[c+3];
        m0 = (m0 >= 0.f) ? m0 : NEG_SLOPE * m0;
        m1 = (m1 >= 0.f) ? m1 : NEG_SLOPE * m1;
        m2 = (m2 >= 0.f) ? m2 : NEG_SLOPE * m2;
        m3 = (m3 >= 0.f) ? m3 : NEG_SLOPE * m3;
        sc0 += m0 * sAtt[h * 16 + c];
        sc1 += m1 * sAtt[h * 16 + c + 1];
        sc2 += m2 * sAtt[h * 16 + c + 2];
        sc3 += m3 * sAtt[h * 16 + c + 3];
    }
    score_csr[gid] = (sc0 + sc1) + (sc2 + sc3);
}

// one WAVE per node; lane = (edge-slot eg 0..3, channel-quad k 0..15, head = k>>2)
__global__ __launch_bounds__(256) void node_pass_kernel(
    const float* __restrict__ score_csr, const float* __restrict__ xl,
    const int4* __restrict__ csr,
    const int* __restrict__ offs, const float* __restrict__ bias,
    float* __restrict__ hout, int N)
{
    int t = threadIdx.x;
    int lane = t & 63;
    int node = blockIdx.x * 4 + (t >> 6);
    if (node >= N) return;
    int eg = lane >> 4;          // edge slot
    int k  = lane & 15;          // channel quad; head = k>>2
    int h  = k >> 2;
    int off = offs[node];
    int deg = offs[node + 1] - off;

    if (deg == 0) {
        if (eg == 0) {
            float4 b = *(const float4*)(bias + k * 4);
            float4 o;
            o.x = fmaxf(b.x, 0.f); o.y = fmaxf(b.y, 0.f);
            o.z = fmaxf(b.z, 0.f); o.w = fmaxf(b.w, 0.f);
            *(float4*)(hout + (size_t)node * 64 + k * 4) = o;
        }
        return;
    }

    // pass 1: head max (exact, order-free)
    float mx = -FLT_MAX;
    for (int j0 = 0; j0 < deg; j0 += 4) {
        int j = j0 + eg;
        if (j < deg) {
            float sc = score_csr[(size_t)(off + j) * 4 + h];
            mx = fmaxf(mx, sc);
        }
    }
    mx = fmaxf(mx, __shfl_xor(mx, 16));
    mx = fmaxf(mx, __shfl_xor(mx, 32));

    // pass 2: 4 edges per iteration, float4 FMA payload
    float4 acc = {0.f, 0.f, 0.f, 0.f};
    float sSum = 0.f;
    for (int j0 = 0; j0 < deg; j0 += 4) {
        int j = j0 + eg;
        int jj = (j < deg) ? j : deg - 1;
        int pos = off + jj;
        int s = csr[pos].x;
        float sc = score_csr[(size_t)pos * 4 + h];
        float ex = (j < deg) ? __expf(sc - mx) : 0.f;
        float4 v = *(const float4*)(xl + (size_t)s * 64 + k * 4);
        acc.x += ex * v.x; acc.y += ex * v.y;
        acc.z += ex * v.z; acc.w += ex * v.w;
        sSum += ex;
    }

    // fixed-grouping butterfly reduce (deterministic)
    acc.x += __shfl_xor(acc.x, 16); acc.y += __shfl_xor(acc.y, 16);
    acc.z += __shfl_xor(acc.z, 16); acc.w += __shfl_xor(acc.w, 16);
    sSum  += __shfl_xor(sSum, 16);
    acc.x += __shfl_xor(acc.x, 32); acc.y += __shfl_xor(acc.y, 32);
    acc.z += __shfl_xor(acc.z, 32); acc.w += __shfl_xor(acc.w, 32);
    sSum  += __shfl_xor(sSum, 32);

    if (eg == 0) {
        float inv = 1.f / sSum;
        float4 b = *(const float4*)(bias + k * 4);
        float4 o;
        o.x = fmaxf(acc.x * inv + b.x, 0.f);
        o.y = fmaxf(acc.y * inv + b.y, 0.f);
        o.z = fmaxf(acc.z * inv + b.z, 0.f);
        o.w = fmaxf(acc.w * inv + b.w, 0.f);
        *(float4*)(hout + (size_t)node * 64 + k * 4) = o;
    }
}

extern "C" void kernel_launch(void* const* d_in, const int* in_sizes, int n_in,
                              void* d_out, int out_size, void* d_ws, size_t ws_size,
                              hipStream_t stream) {
    const float* x    = (const float*)d_in[0];
    const int*   eidx = (const int*)d_in[1];
    const float* ea   = (const float*)d_in[2];
    const float* Wl   = (const float*)d_in[3];
    const float* bl   = (const float*)d_in[4];
    const float* Wr   = (const float*)d_in[5];
    const float* br   = (const float*)d_in[6];
    const float* We   = (const float*)d_in[7];
    const float* att  = (const float*)d_in[8];
    const float* bias = (const float*)d_in[9];
    float* out = (float*)d_out;

    const int N = in_sizes[0] / 64;
    const int E = in_sizes[1] / 2;
    const int* src = eidx;
    const int* dst = eidx + E;

    float* ws = (float*)d_ws;
    float* xl      = ws;                               // N*64
    float* xr      = xl + (size_t)N * 64;              // N*64
    float* score   = xr + (size_t)N * 64;              // E*4
    float* h_tmp   = score + (size_t)E * 4;            // N*64
    int* counts    = (int*)(h_tmp + (size_t)N * 64);   // N
    int* cursor    = counts + N;                       // N
    int* offs      = cursor + N;                       // N+1
    int* bsums     = offs + N + 1;                     // 64
    uintptr_t p    = (uintptr_t)(bsums + 64);
    p = (p + 15) & ~(uintptr_t)15;
    int4* csr      = (int4*)p;                         // E int4 (16B aligned)

    dim3 blk(256);
    int g_n    = (N + 255) / 256;
    int g_e    = (E + 255) / 256;
    int g_e4   = (E + 1023) / 1024;
    int g_eh   = (E * 4 + 255) / 256;
    int g_gemm = (N + 63) / 64;
    int g_node = (N + 3) / 4;
    int NB     = (N + 1023) / 1024;   // 49 for N=50000 (<= 64)

    // CSR over dst, canonical eid order (edge_index is layer-invariant)
    zero_kernel<<<g_n, blk, 0, stream>>>(counts, cursor, N);
    count_kernel<<<g_e, blk, 0, stream>>>(dst, counts, E);
    scan_bsums_kernel<<<NB, blk, 0, stream>>>(counts, bsums, N);
    scan_bscan_kernel<<<1, 64, 0, stream>>>(bsums, NB);
    scan_final_kernel<<<NB, blk, 0, stream>>>(counts, bsums, offs, N);
    scatter_kernel<<<g_e4, blk, 0, stream>>>(src, dst, offs, cursor, csr, E);
    sort_segments_kernel<<<g_node, blk, 0, stream>>>(csr, offs, N);

    const float* hin = x;
    for (int l = 0; l < 3; ++l) {
        float* hout = (l == 2) ? out : h_tmp;
        node_gemm_kernel<<<g_gemm, blk, 0, stream>>>(hin, Wl + (size_t)l * 4096, bl + l * 64,
                                                     Wr + (size_t)l * 4096, br + l * 64, xl, xr, N);
        edge_score_kernel<<<g_eh, blk, 0, stream>>>(xl, xr, ea, csr,
                                                    We + (size_t)l * 1024, att + l * 64,
                                                    score, E);
        node_pass_kernel<<<g_node, blk, 0, stream>>>(score, xl, csr, offs,
                                                     bias + l * 64, hout, N);
        hin = hout;
    }
}